// Round 1
// baseline (180.062 us; speedup 1.0000x reference)
//
#include <hip/hip_runtime.h>

// Predictive-coding graph message passing, MI355X.
// Layout strategy: node state transposed to [N][B] (B=32) so one half-wave
// (32 lanes = 32 batches) handles one edge: edge indices/weight read ONCE per
// edge (LDS broadcast), gather + scatter are each a single aligned 128B line.

static constexpr int kB = 32;     // batch size (fixed by problem)
static constexpr int kLogB = 5;

// K1: transpose x into [N][B], compute tanh, zero the two accumulators.
__global__ void __launch_bounds__(256) k_init(
    const float* __restrict__ x, float* __restrict__ x_t,
    float* __restrict__ fx_t, float* __restrict__ mu_t,
    float* __restrict__ acc_t, int N, int total) {
  int j = blockIdx.x * blockDim.x + threadIdx.x;   // j = n*B + b
  if (j >= total) return;
  int n = j >> kLogB, b = j & (kB - 1);
  float xv = x[b * N + n];
  float fx = tanhf(xv);
  x_t[j]  = xv;
  fx_t[j] = fx;
  mu_t[j]  = 0.0f;
  acc_t[j] = 0.0f;
}

// K2/K4: acc[sidx[e]*B + b] += w[e] * vals[gidx[e]*B + b]  for all e, b.
// Half-wave = one edge across 32 batches; EPB edges staged in LDS per block.
template <int EPB>
__global__ void __launch_bounds__(256) k_scatter(
    const int* __restrict__ gidx, const int* __restrict__ sidx,
    const float* __restrict__ w, const float* __restrict__ vals,
    float* __restrict__ acc, int E) {
  __shared__ int   s_g[EPB];
  __shared__ int   s_s[EPB];
  __shared__ float s_w[EPB];
  int e0 = blockIdx.x * EPB;
  int nloc = min(EPB, E - e0);
  for (int t = threadIdx.x; t < nloc; t += 256) {
    int e = e0 + t;
    s_g[t] = gidx[e];
    s_s[t] = sidx[e];
    s_w[t] = w[e];
  }
  __syncthreads();
  int b  = threadIdx.x & (kB - 1);
  int eg = threadIdx.x >> kLogB;           // 8 edge slots per 256-thread block
  for (int el = eg; el < nloc; el += (256 >> kLogB)) {
    int g = s_g[el];                        // LDS broadcast within half-wave
    int s = s_s[el];
    float wv = s_w[el];
    float v = vals[(g << kLogB) + b];       // coalesced 128B line per half-wave
    unsafeAtomicAdd(&acc[(s << kLogB) + b], wv * v);  // global_atomic_add_f32
  }
}

// K3: eps = x - mu (transposed space); emit mu output in batch-major layout.
__global__ void __launch_bounds__(256) k_eps(
    const float* __restrict__ x_t, const float* __restrict__ mu_t,
    float* __restrict__ eps_t, float* __restrict__ out_mu, int N, int total) {
  int j = blockIdx.x * blockDim.x + threadIdx.x;
  if (j >= total) return;
  float mu = mu_t[j];
  eps_t[j] = x_t[j] - mu;
  int n = j >> kLogB, b = j & (kB - 1);
  out_mu[b * N + n] = mu;
}

// K5: dx = -eps + (1 - fx^2) * acc; emit in batch-major layout.
__global__ void __launch_bounds__(256) k_fin(
    const float* __restrict__ fx_t, const float* __restrict__ eps_t,
    const float* __restrict__ acc_t, float* __restrict__ out_dx,
    int N, int total) {
  int j = blockIdx.x * blockDim.x + threadIdx.x;
  if (j >= total) return;
  float fx = fx_t[j];
  float dx = fmaf(1.0f - fx * fx, acc_t[j], -eps_t[j]);
  int n = j >> kLogB, b = j & (kB - 1);
  out_dx[b * N + n] = dx;
}

extern "C" void kernel_launch(void* const* d_in, const int* in_sizes, int n_in,
                              void* d_out, int out_size, void* d_ws, size_t ws_size,
                              hipStream_t stream) {
  const float* x    = (const float*)d_in[0];
  const float* w    = (const float*)d_in[1];
  const int*   esrc = (const int*)d_in[2];
  const int*   edst = (const int*)d_in[3];

  const int BN = in_sizes[0];        // B * N = 131072
  const int E  = in_sizes[1];        // 524288
  const int N  = BN / kB;            // 4096

  float* ws    = (float*)d_ws;
  float* x_t   = ws;                 // [BN]
  float* fx_t  = ws + (size_t)BN;    // [BN]
  float* mu_t  = ws + 2 * (size_t)BN;
  float* eps_t = ws + 3 * (size_t)BN;
  float* acc_t = ws + 4 * (size_t)BN;

  float* out_mu = (float*)d_out;
  float* out_dx = (float*)d_out + BN;

  constexpr int EPB = 256;           // edges per block in scatter kernels
  int nblk_nodes = (BN + 255) / 256;
  int nblk_edges = (E + EPB - 1) / EPB;   // 2048 blocks

  k_init<<<nblk_nodes, 256, 0, stream>>>(x, x_t, fx_t, mu_t, acc_t, N, BN);
  // Pass 1: mu[dst] += w * fx[src]
  k_scatter<EPB><<<nblk_edges, 256, 0, stream>>>(esrc, edst, w, fx_t, mu_t, E);
  k_eps<<<nblk_nodes, 256, 0, stream>>>(x_t, mu_t, eps_t, out_mu, N, BN);
  // Pass 2: acc[src] += w * eps[dst]
  k_scatter<EPB><<<nblk_edges, 256, 0, stream>>>(edst, esrc, w, eps_t, acc_t, E);
  k_fin<<<nblk_nodes, 256, 0, stream>>>(fx_t, eps_t, acc_t, out_dx, N, BN);
}